// Round 1
// baseline (1167.338 us; speedup 1.0000x reference)
//
#include <hip/hip_runtime.h>
#include <hip/hip_bf16.h>

// Problem constants (fixed by setup_inputs)
constexpr int B_ = 8;
constexpr int H_ = 120;
constexpr int W_ = 160;
constexpr int N_ = H_ * W_;     // 19200
constexpr int C_ = 96;
constexpr int NH_ = 3;
constexpr int D_ = 32;
constexpr int KMAX_ = 24;       // c/4
constexpr int NCOL = 288;       // 192 (qk) + 96 (v)

constexpr int T1 = 64;                       // pass1 tile rows
constexpr int GX1 = 75;                      // pass1 blocks per (s,b)
constexpr int TPB1 = (N_ / T1) / GX1;        // 4 tiles per block
constexpr int T2 = 64;                       // pass2 tile rows
constexpr int NT2 = N_ / T2;                 // 300

// ---------------------------------------------------------------- rope table
__global__ void rope_table_kernel(float* __restrict__ cs, float* __restrict__ sn) {
    int idx = blockIdx.x * 256 + threadIdx.x;
    if (idx >= N_ * 48) return;
    int p = idx % 48, npos = idx / 48;
    int ih = npos / W_, iw = npos % W_;
    int j = (p < KMAX_) ? p : (p - KMAX_);
    float pos = (p < KMAX_) ? (float)ih : (float)iw;
    // theta = 10000^(-j/24)
    float theta = expf(-(float)j * (9.210340371976184f / (float)KMAX_));
    float ang = pos * theta;
    float s, c;
    sincosf(ang, &s, &c);
    cs[idx] = c;
    sn[idx] = s;
}

// ---------------------------------------------------------------- pass 1
// Per tile of 64 rows: qkv = x @ [Wqk;Wv]^T + bias ; elu+1 on q,k ;
// store q (pre-rope) and v as bf16 ; rope k ; accumulate kv, kmean partials.
__global__ __launch_bounds__(256, 2)
void pass1_kernel(const float* __restrict__ x1, const float* __restrict__ x2,
                  const float* __restrict__ Wqk, const float* __restrict__ bqk,
                  const float* __restrict__ Wv, const float* __restrict__ bv,
                  const float* __restrict__ cs, const float* __restrict__ sn,
                  __hip_bfloat16* __restrict__ qbuf, __hip_bfloat16* __restrict__ vbuf,
                  float* __restrict__ kvpart, float* __restrict__ kmpart)
{
    __shared__ float smem[15680];            // 62.7 KB
    float* xs   = smem;                      // GEMM:     [64][97]
    float* wS   = smem + 6208;               // GEMM:     [32][296]
    float* kraw = smem;                      // epilogue: [64][97]
    float* vsm  = smem + 6208;               // epilogue: [64][97]

    const int tid = threadIdx.x;
    const int gx = blockIdx.x, b = blockIdx.y, s = blockIdx.z;
    const float* x = s ? x2 : x1;
    const int rt = tid >> 5, ct = tid & 31;  // 8 row-groups x 32 col-groups

    float bias[9];
#pragma unroll
    for (int j = 0; j < 9; ++j) {
        int col = ct + 32 * j;
        bias[j] = (col < 192) ? bqk[col] : bv[col - 192];
    }

    float kvacc[3][4] = {};
    float kmacc = 0.f;
    const int d0 = (tid >> 4) * 2;   // even 0..30
    const int e0 = (tid & 15) * 2;

    for (int t = 0; t < TPB1; ++t) {
        const int n0 = (gx * TPB1 + t) * T1;
        __syncthreads();
        // stage x tile
        const float* xb = x + ((size_t)b * N_ + n0) * C_;
        for (int i = tid; i < T1 * C_; i += 256) {
            int r = i / C_, ch = i % C_;
            xs[r * 97 + ch] = xb[i];
        }
        float acc[9][8] = {};
        for (int kc = 0; kc < 3; ++kc) {
            __syncthreads();
            for (int i = tid; i < NCOL * 32; i += 256) {
                int col = i >> 5, kk = i & 31;
                float wv = (col < 192) ? Wqk[col * C_ + kc * 32 + kk]
                                       : Wv[(col - 192) * C_ + kc * 32 + kk];
                wS[kk * 296 + col] = wv;
            }
            __syncthreads();
#pragma unroll 4
            for (int kk = 0; kk < 32; ++kk) {
                float xv[8];
#pragma unroll
                for (int i = 0; i < 8; ++i) xv[i] = xs[(rt * 8 + i) * 97 + kc * 32 + kk];
#pragma unroll
                for (int j = 0; j < 9; ++j) {
                    float wv = wS[kk * 296 + ct + 32 * j];
#pragma unroll
                    for (int i = 0; i < 8; ++i) acc[j][i] = fmaf(xv[i], wv, acc[j][i]);
                }
            }
        }
        // ---- epilogue: cols j 0..2 = q, 3..5 = k, 6..8 = v
        __hip_bfloat16* qb = qbuf + ((size_t)(s * B_ + b) * N_ + n0) * C_;
        __hip_bfloat16* vb = vbuf + ((size_t)(s * B_ + b) * N_ + n0) * C_;
#pragma unroll
        for (int j = 0; j < 3; ++j) {
            int ch = ct + 32 * j;
#pragma unroll
            for (int i = 0; i < 8; ++i) {
                float q = acc[j][i] + bias[j];
                q = (q > 0.f) ? q + 1.f : __expf(q);         // elu(q)+1
                qb[(size_t)(rt * 8 + i) * C_ + ch] = __float2bfloat16(q);
            }
        }
        __syncthreads();  // all GEMM LDS reads done -> reuse smem
#pragma unroll
        for (int j = 0; j < 3; ++j) {
            int ch = ct + 32 * j;
#pragma unroll
            for (int i = 0; i < 8; ++i) {
                float k = acc[j + 3][i] + bias[j + 3];
                k = (k > 0.f) ? k + 1.f : __expf(k);
                kraw[(rt * 8 + i) * 97 + ch] = k;
                float v = acc[j + 6][i] + bias[j + 6];
                vsm[(rt * 8 + i) * 97 + ch] = v;
                vb[(size_t)(rt * 8 + i) * C_ + ch] = __float2bfloat16(v);
            }
        }
        __syncthreads();
        // kmean partial (non-roped k)
        if (tid < C_) {
            float s2 = 0.f;
            for (int r = 0; r < T1; ++r) s2 += kraw[r * 97 + tid];
            kmacc += s2;
        }
        __syncthreads();
        // rope k in place
#pragma unroll
        for (int u = 0; u < (T1 * 48) / 256; ++u) {   // 12
            int idx = u * 256 + tid;
            int r = idx / 48, p = idx % 48;
            float c  = cs[(size_t)(n0 + r) * 48 + p];
            float sv = sn[(size_t)(n0 + r) * 48 + p];
            float re = kraw[r * 97 + 2 * p], im = kraw[r * 97 + 2 * p + 1];
            kraw[r * 97 + 2 * p]     = c * re - sv * im;
            kraw[r * 97 + 2 * p + 1] = sv * re + c * im;
        }
        __syncthreads();
        // kv partial: kv[h][d][e] += k_r[r][h*32+d] * v[r][h*32+e]
        for (int r = 0; r < T1; ++r) {
#pragma unroll
            for (int hh = 0; hh < 3; ++hh) {
                float k0 = kraw[r * 97 + hh * 32 + d0];
                float k1 = kraw[r * 97 + hh * 32 + d0 + 1];
                float v0 = vsm[r * 97 + hh * 32 + e0];
                float v1 = vsm[r * 97 + hh * 32 + e0 + 1];
                kvacc[hh][0] = fmaf(k0, v0, kvacc[hh][0]);
                kvacc[hh][1] = fmaf(k0, v1, kvacc[hh][1]);
                kvacc[hh][2] = fmaf(k1, v0, kvacc[hh][2]);
                kvacc[hh][3] = fmaf(k1, v1, kvacc[hh][3]);
            }
        }
    }
    // write partials (deterministic two-stage reduction, no atomics)
    float* kvp = kvpart + ((size_t)(s * B_ + b) * GX1 + gx) * (NH_ * D_ * D_);
#pragma unroll
    for (int hh = 0; hh < 3; ++hh) {
        kvp[hh * 1024 + d0 * 32 + e0]           = kvacc[hh][0];
        kvp[hh * 1024 + d0 * 32 + e0 + 1]       = kvacc[hh][1];
        kvp[hh * 1024 + (d0 + 1) * 32 + e0]     = kvacc[hh][2];
        kvp[hh * 1024 + (d0 + 1) * 32 + e0 + 1] = kvacc[hh][3];
    }
    if (tid < C_) kmpart[((size_t)(s * B_ + b) * GX1 + gx) * C_ + tid] = kmacc;
}

// ---------------------------------------------------------------- reduce
__global__ void reduce_kernel(const float* __restrict__ kvpart, const float* __restrict__ kmpart,
                              float* __restrict__ kvbuf, float* __restrict__ kmbuf)
{
    int idx = blockIdx.x * 256 + threadIdx.x;
    const float invN = 1.0f / (float)N_;
    if (idx < 2 * B_ * 3072) {
        int sb = idx / 3072, e = idx % 3072;
        float acc = 0.f;
        for (int g = 0; g < GX1; ++g) acc += kvpart[((size_t)sb * GX1 + g) * 3072 + e];
        kvbuf[idx] = acc * invN;
    } else if (idx < 2 * B_ * 3072 + 2 * B_ * C_) {
        int j = idx - 2 * B_ * 3072;
        int sb = j / C_, ch = j % C_;
        float acc = 0.f;
        for (int g = 0; g < GX1; ++g) acc += kmpart[((size_t)sb * GX1 + g) * C_ + ch];
        kmbuf[j] = acc * invN;
    }
}

// ---------------------------------------------------------------- pass 2
__global__ __launch_bounds__(256, 2)
void pass2_kernel(const __hip_bfloat16* __restrict__ qbuf, const __hip_bfloat16* __restrict__ vbuf,
                  const float* __restrict__ kvbuf, const float* __restrict__ kmbuf,
                  const float* __restrict__ cs, const float* __restrict__ sn,
                  const float* __restrict__ lw, const float* __restrict__ lb,
                  float* __restrict__ out)
{
    __shared__ __hip_bfloat16 qsm[T2 * 100];
    __shared__ float osm[T2 * 98];
    __shared__ float kvL[3 * 32 * 32];
    __shared__ float lwL[96 * 9];
    __shared__ float lbL[96];
    __shared__ float kmL[96];
    __shared__ float zsh[3 * T2];

    const int tid = threadIdx.x;
    const int tile = blockIdx.x, b = blockIdx.y, s = blockIdx.z;
    const int so = 1 - s;
    const int n0 = tile * T2;

    const float* kvsrc = kvbuf + (size_t)(so * B_ + b) * 3072;
    for (int i = tid; i < 3072; i += 256) kvL[i] = kvsrc[i];
    for (int i = tid; i < 96 * 9; i += 256) lwL[i] = lw[i];
    if (tid < 96) { lbL[tid] = lb[tid]; kmL[tid] = kmbuf[(so * B_ + b) * 96 + tid]; }

    const __hip_bfloat16* qb = qbuf + ((size_t)(s * B_ + b) * N_ + n0) * C_;
    for (int i = tid; i < T2 * C_; i += 256) {
        int r = i / C_, ch = i % C_;
        qsm[r * 100 + ch] = qb[i];
    }
    __syncthreads();
    // z from NON-roped q vs kmean of other stream
    if (tid < 192) {
        int r = tid & 63, hh = tid >> 6;
        float acc = 0.f;
        for (int dd = 0; dd < 32; ++dd)
            acc += __bfloat162float(qsm[r * 100 + hh * 32 + dd]) * kmL[hh * 32 + dd];
        zsh[hh * 64 + r] = 1.f / (acc + 1e-6f);
    }
    __syncthreads();
    // rope q in place
#pragma unroll
    for (int u = 0; u < (T2 * 48) / 256; ++u) {  // 12
        int idx = u * 256 + tid;
        int r = idx / 48, p = idx % 48;
        float c  = cs[(size_t)(n0 + r) * 48 + p];
        float sv = sn[(size_t)(n0 + r) * 48 + p];
        float re = __bfloat162float(qsm[r * 100 + 2 * p]);
        float im = __bfloat162float(qsm[r * 100 + 2 * p + 1]);
        qsm[r * 100 + 2 * p]     = __float2bfloat16(c * re - sv * im);
        qsm[r * 100 + 2 * p + 1] = __float2bfloat16(sv * re + c * im);
    }
    __syncthreads();
    // o = (q_r @ kv_other) * z  -> osm
    {
        const int rl = tid & 31, cg = tid >> 5;
#pragma unroll
        for (int rh = 0; rh < 2; ++rh) {
            int r = rl + 32 * rh;
#pragma unroll
            for (int g = 0; g < 3; ++g) {
                int ch0 = cg * 12 + g * 4;
                int hh = ch0 >> 5, ee = ch0 & 31;
                float a0 = 0, a1 = 0, a2 = 0, a3 = 0;
                for (int d = 0; d < 32; ++d) {
                    float qv = __bfloat162float(qsm[r * 100 + hh * 32 + d]);
                    const float* kp = &kvL[hh * 1024 + d * 32 + ee];
                    a0 = fmaf(qv, kp[0], a0);
                    a1 = fmaf(qv, kp[1], a1);
                    a2 = fmaf(qv, kp[2], a2);
                    a3 = fmaf(qv, kp[3], a3);
                }
                float z = zsh[hh * 64 + r];
                osm[r * 98 + ch0]     = a0 * z;
                osm[r * 98 + ch0 + 1] = a1 * z;
                osm[r * 98 + ch0 + 2] = a2 * z;
                osm[r * 98 + ch0 + 3] = a3 * z;
            }
        }
    }
    __syncthreads();
    // LePE: osm += depthwise 3x3 conv(v) + lepe_b  (channel-major mapping: coalesced vbuf reads)
    const __hip_bfloat16* vb = vbuf + (size_t)(s * B_ + b) * N_ * C_;
#pragma unroll
    for (int t = 0; t < (T2 * C_) / 256; ++t) {  // 24
        int u = t * 256 + tid;
        int ch = u % C_, r = u / C_;
        int npos = n0 + r;
        int ih = npos / W_, iw = npos - ih * W_;
        float acc = lbL[ch];
#pragma unroll
        for (int ky = 0; ky < 3; ++ky) {
            int ih2 = ih + ky - 1;
            if (ih2 < 0 || ih2 >= H_) continue;
#pragma unroll
            for (int kx = 0; kx < 3; ++kx) {
                int iw2 = iw + kx - 1;
                if (iw2 < 0 || iw2 >= W_) continue;
                float vv = __bfloat162float(vb[(size_t)(ih2 * W_ + iw2) * C_ + ch]);
                acc = fmaf(vv, lwL[ch * 9 + ky * 3 + kx], acc);
            }
        }
        osm[r * 98 + ch] += acc;
    }
    __syncthreads();
    // store transposed: out[b][ch][npos]  (n-major mapping: coalesced writes)
    float* ob = out + (size_t)(s * B_ + b) * C_ * N_;
#pragma unroll
    for (int t = 0; t < (T2 * C_) / 256; ++t) {
        int u = t * 256 + tid;
        int r = u & 63, ch = u >> 6;
        ob[(size_t)ch * N_ + n0 + r] = osm[r * 98 + ch];
    }
}

// ---------------------------------------------------------------- launch
extern "C" void kernel_launch(void* const* d_in, const int* in_sizes, int n_in,
                              void* d_out, int out_size, void* d_ws, size_t ws_size,
                              hipStream_t stream)
{
    const float* x1  = (const float*)d_in[0];
    const float* x2  = (const float*)d_in[1];
    const float* Wqk = (const float*)d_in[2];
    const float* bqk = (const float*)d_in[3];
    const float* Wv  = (const float*)d_in[4];
    const float* bv  = (const float*)d_in[5];
    const float* lw  = (const float*)d_in[6];
    const float* lb  = (const float*)d_in[7];
    float* out = (float*)d_out;

    char* ws = (char*)d_ws;
    size_t off = 0;
    auto alloc = [&](size_t bytes) -> void* {
        void* p = ws + off;
        off = (off + bytes + 255) & ~(size_t)255;
        return p;
    };
    float* cs = (float*)alloc(sizeof(float) * (size_t)N_ * 48);
    float* sn = (float*)alloc(sizeof(float) * (size_t)N_ * 48);
    __hip_bfloat16* qbuf = (__hip_bfloat16*)alloc(2ull * B_ * N_ * C_ * sizeof(__hip_bfloat16));
    __hip_bfloat16* vbuf = (__hip_bfloat16*)alloc(2ull * B_ * N_ * C_ * sizeof(__hip_bfloat16));
    float* kvpart = (float*)alloc(2ull * B_ * GX1 * 3072 * sizeof(float));
    float* kmpart = (float*)alloc(2ull * B_ * GX1 * C_ * sizeof(float));
    float* kvbuf  = (float*)alloc(2ull * B_ * 3072 * sizeof(float));
    float* kmbuf  = (float*)alloc(2ull * B_ * C_ * sizeof(float));

    hipLaunchKernelGGL(rope_table_kernel, dim3((N_ * 48 + 255) / 256), dim3(256), 0, stream, cs, sn);
    hipLaunchKernelGGL(pass1_kernel, dim3(GX1, B_, 2), dim3(256), 0, stream,
                       x1, x2, Wqk, bqk, Wv, bv, cs, sn, qbuf, vbuf, kvpart, kmpart);
    hipLaunchKernelGGL(reduce_kernel, dim3((2 * B_ * 3072 + 2 * B_ * C_ + 255) / 256), dim3(256), 0, stream,
                       kvpart, kmpart, kvbuf, kmbuf);
    hipLaunchKernelGGL(pass2_kernel, dim3(NT2, B_, 2), dim3(256), 0, stream,
                       qbuf, vbuf, kvbuf, kmbuf, cs, sn, lw, lb, out);
}

// Round 3
// 766.676 us; speedup vs baseline: 1.5226x; 1.5226x over previous
//
#include <hip/hip_runtime.h>
#include <hip/hip_bf16.h>

// Problem constants (fixed by setup_inputs)
constexpr int B_ = 8;
constexpr int H_ = 120;
constexpr int W_ = 160;
constexpr int N_ = H_ * W_;     // 19200
constexpr int C_ = 96;

constexpr int GX1 = 75;         // pass1 blocks per (s,b)
constexpr int TPB1 = 4;         // tiles of 64 rows per block
constexpr int NT2 = N_ / 64;    // 300

typedef __attribute__((ext_vector_type(8))) short s16x8;
typedef __attribute__((ext_vector_type(4))) float f32x4;

static __device__ inline unsigned short f2bf(float f) {
    unsigned u = __float_as_uint(f);
    return (unsigned short)((u + 0x7FFFu + ((u >> 16) & 1u)) >> 16);
}
static __device__ inline float bf2f(unsigned short h) {
    return __uint_as_float(((unsigned)h) << 16);
}
static __device__ inline void MFMA(f32x4& c, s16x8 a, s16x8 b) {
    c = __builtin_amdgcn_mfma_f32_16x16x32_bf16(a, b, c, 0, 0, 0);
}
// frag-order LDS index for [96ch][64r] bf16 tiles:
// addr = (((r>>5)*6 + chT)*64 + ((r>>3)&3)*16 + chLo)*8 + (r&7)
static __device__ inline int kvidx(int chT, int chLo, int r) {
    return ((r >> 5) * 6 + chT) * 512 + ((r >> 3) & 3) * 128 + chLo * 8 + (r & 7);
}

// ---------------------------------------------------------------- rope tables (transposed: [48][N])
__global__ void rope_table_kernel(float* __restrict__ csT, float* __restrict__ snT) {
    int idx = blockIdx.x * 256 + threadIdx.x;
    if (idx >= 48 * N_) return;
    int p = idx / N_, n = idx - p * N_;
    int ih = n / W_, iw = n - ih * W_;
    int j = (p < 24) ? p : (p - 24);
    float pos = (p < 24) ? (float)ih : (float)iw;
    float theta = expf(-(float)j * (9.210340371976184f / 24.0f));
    float s, c;
    sincosf(pos * theta, &s, &c);
    csT[idx] = c;
    snT[idx] = s;
}

// ---------------------------------------------------------------- pass 1 (MFMA)
__global__ __launch_bounds__(256, 2)
void pass1_kernel(const float* __restrict__ x1, const float* __restrict__ x2,
                  const float* __restrict__ Wqk, const float* __restrict__ bqk,
                  const float* __restrict__ Wv, const float* __restrict__ bv,
                  const float* __restrict__ csT, const float* __restrict__ snT,
                  unsigned short* __restrict__ qbuf, unsigned short* __restrict__ vbuf,
                  float* __restrict__ kvpart, float* __restrict__ kmpart)
{
    __shared__ alignas(16) unsigned short Wl[27648];   // 55296 B, frag-order [3 ks][18 cT][64 lane][8]
    __shared__ alignas(16) unsigned short kTl[6144];   // 12288 B, frag-order [96ch][64r]
    __shared__ alignas(16) unsigned short vTl[6144];   // 12288 B

    const int tid = threadIdx.x;
    const int l = tid & 63, w = tid >> 6;
    const int gx = blockIdx.x, b = blockIdx.y, s = blockIdx.z;
    const float* x = s ? x2 : x1;
    const int sb = s * B_ + b;

    // stage W in fragment order (bf16)
    for (int i = tid; i < 3456; i += 256) {
        int s3 = i / 1152, rem = i - s3 * 1152;
        int cT = rem >> 6, lane = rem & 63;
        int col = cT * 16 + (lane & 15), k0 = s3 * 32 + 8 * (lane >> 4);
        const float* wp = (col < 192) ? (Wqk + col * 96 + k0) : (Wv + (col - 192) * 96 + k0);
        f32x4 wa = *(const f32x4*)wp;
        f32x4 wb = *(const f32x4*)(wp + 4);
        s16x8 wf;
        wf[0] = (short)f2bf(wa[0]); wf[1] = (short)f2bf(wa[1]);
        wf[2] = (short)f2bf(wa[2]); wf[3] = (short)f2bf(wa[3]);
        wf[4] = (short)f2bf(wb[0]); wf[5] = (short)f2bf(wb[1]);
        wf[6] = (short)f2bf(wb[2]); wf[7] = (short)f2bf(wb[3]);
        *(s16x8*)&Wl[i * 8] = wf;
    }
    float biasv[18];
#pragma unroll
    for (int cT = 0; cT < 18; ++cT) {
        int col = cT * 16 + (l & 15);
        biasv[cT] = (col < 192) ? bqk[col] : bv[col - 192];
    }
    f32x4 kvacc[3] = {};
    float kmacc[6] = {};
    __syncthreads();

    for (int t = 0; t < TPB1; ++t) {
        const int n0 = (gx * TPB1 + t) * 64;
        // GEMM: wave w computes rows [16w,16w+16) x 288 cols
        f32x4 acc[18] = {};
        const float* xrow = x + ((size_t)b * N_ + n0 + 16 * w + (l & 15)) * 96 + 8 * (l >> 4);
#pragma unroll
        for (int s3 = 0; s3 < 3; ++s3) {
            f32x4 xa = *(const f32x4*)(xrow + s3 * 32);
            f32x4 xb = *(const f32x4*)(xrow + s3 * 32 + 4);
            s16x8 af;
            af[0] = (short)f2bf(xa[0]); af[1] = (short)f2bf(xa[1]);
            af[2] = (short)f2bf(xa[2]); af[3] = (short)f2bf(xa[3]);
            af[4] = (short)f2bf(xb[0]); af[5] = (short)f2bf(xb[1]);
            af[6] = (short)f2bf(xb[2]); af[7] = (short)f2bf(xb[3]);
#pragma unroll
            for (int cT = 0; cT < 18; ++cT) {
                s16x8 bf = *(const s16x8*)&Wl[((s3 * 18 + cT) * 64 + l) * 8];
                MFMA(acc[cT], af, bf);
            }
        }
        __syncthreads();   // prev tile's kv-MFMA reads of kTl/vTl complete

        // epilogue
        const int r0 = 16 * w + 4 * (l >> 4);
        unsigned short* qb = qbuf + ((size_t)sb * N_ + n0) * 96;
        unsigned short* vb = vbuf + ((size_t)sb * N_ + n0) * 96;
#pragma unroll
        for (int cT = 0; cT < 6; ++cT) {          // q: elu+1, store pre-rope
#pragma unroll
            for (int i2 = 0; i2 < 4; ++i2) {
                float q = acc[cT][i2] + biasv[cT];
                q = (q > 0.f) ? q + 1.f : __expf(q);
                qb[(size_t)(r0 + i2) * 96 + cT * 16 + (l & 15)] = f2bf(q);
            }
        }
#pragma unroll
        for (int cT = 6; cT < 12; ++cT) {         // k: elu+1, kmean, stage to LDS
            float colsum = 0.f;
#pragma unroll
            for (int i2 = 0; i2 < 4; ++i2) {
                float k = acc[cT][i2] + biasv[cT];
                k = (k > 0.f) ? k + 1.f : __expf(k);
                colsum += k;
                kTl[kvidx(cT - 6, l & 15, r0 + i2)] = f2bf(k);
            }
            colsum += __shfl_xor(colsum, 16, 64);
            colsum += __shfl_xor(colsum, 32, 64);
            kmacc[cT - 6] += colsum;
        }
#pragma unroll
        for (int cT = 12; cT < 18; ++cT) {        // v: store + stage to LDS
#pragma unroll
            for (int i2 = 0; i2 < 4; ++i2) {
                float v = acc[cT][i2] + biasv[cT];
                unsigned short hv = f2bf(v);
                vb[(size_t)(r0 + i2) * 96 + (cT - 12) * 16 + (l & 15)] = hv;
                vTl[kvidx(cT - 12, l & 15, r0 + i2)] = hv;
            }
        }
        __syncthreads();
        // rope k in LDS (channel pairs 2p,2p+1 = adjacent chunks)
        for (int u = tid; u < 384; u += 256) {
            int p = u % 48, sub = u / 48;
            int ks = sub >> 2, rg = sub & 3;
            int chunk = ((ks * 6 + (p >> 3)) << 6) + (rg << 4) + ((2 * p) & 15);
            s16x8 re8 = *(s16x8*)&kTl[chunk * 8];
            s16x8 im8 = *(s16x8*)&kTl[chunk * 8 + 8];
            const float* cp = csT + (size_t)p * N_ + n0 + ks * 32 + rg * 8;
            const float* sp = snT + (size_t)p * N_ + n0 + ks * 32 + rg * 8;
            f32x4 c0 = *(const f32x4*)cp, c1 = *(const f32x4*)(cp + 4);
            f32x4 s0 = *(const f32x4*)sp, s1 = *(const f32x4*)(sp + 4);
            s16x8 ro, io;
#pragma unroll
            for (int e = 0; e < 4; ++e) {
                float re = bf2f((unsigned short)re8[e]), im = bf2f((unsigned short)im8[e]);
                ro[e] = (short)f2bf(c0[e] * re - s0[e] * im);
                io[e] = (short)f2bf(s0[e] * re + c0[e] * im);
            }
#pragma unroll
            for (int e = 0; e < 4; ++e) {
                float re = bf2f((unsigned short)re8[e + 4]), im = bf2f((unsigned short)im8[e + 4]);
                ro[e + 4] = (short)f2bf(c1[e] * re - s1[e] * im);
                io[e + 4] = (short)f2bf(s1[e] * re + c1[e] * im);
            }
            *(s16x8*)&kTl[chunk * 8] = ro;
            *(s16x8*)&kTl[chunk * 8 + 8] = io;
        }
        __syncthreads();
        // kv += k_roped^T @ v  (wave w owns flat C-tiles {w, w+4, w+8})
#pragma unroll
        for (int j = 0; j < 3; ++j) {
            int f = w + 4 * j;
            int h = f >> 2, dT = (f >> 1) & 1, eT = f & 1;
#pragma unroll
            for (int ks = 0; ks < 2; ++ks) {
                s16x8 a = *(const s16x8*)&kTl[(((ks * 6 + (h * 2 + dT)) << 6) + l) * 8];
                s16x8 bb = *(const s16x8*)&vTl[(((ks * 6 + (h * 2 + eT)) << 6) + l) * 8];
                MFMA(kvacc[j], a, bb);
            }
        }
    }
    // write partials
    float* kvp = kvpart + ((size_t)sb * GX1 + gx) * 3072;
#pragma unroll
    for (int j = 0; j < 3; ++j) {
        int f = w + 4 * j;
        int h = f >> 2, dT = (f >> 1) & 1, eT = f & 1;
#pragma unroll
        for (int i2 = 0; i2 < 4; ++i2)
            kvp[h * 1024 + (dT * 16 + 4 * (l >> 4) + i2) * 32 + eT * 16 + (l & 15)] = kvacc[j][i2];
    }
    if (l < 16) {
        float* kmp = kmpart + ((size_t)((size_t)sb * GX1 + gx) * 4 + w) * 96;
#pragma unroll
        for (int j6 = 0; j6 < 6; ++j6) kmp[j6 * 16 + l] = kmacc[j6];
    }
}

// ---------------------------------------------------------------- reduce
__global__ void reduce_kernel(const float* __restrict__ kvpart, const float* __restrict__ kmpart,
                              float* __restrict__ kvbuf, float* __restrict__ kmbuf)
{
    int idx = blockIdx.x * 256 + threadIdx.x;
    const float invN = 1.0f / (float)N_;
    if (idx < 16 * 3072) {
        int sb = idx / 3072, e = idx - sb * 3072;
        float acc = 0.f;
        for (int g = 0; g < GX1; ++g) acc += kvpart[((size_t)sb * GX1 + g) * 3072 + e];
        kvbuf[idx] = acc * invN;
    } else if (idx < 16 * 3072 + 16 * 96) {
        int j = idx - 16 * 3072;
        int sb = j / 96, ch = j - sb * 96;
        float acc = 0.f;
        for (int g = 0; g < GX1 * 4; ++g) acc += kmpart[((size_t)sb * GX1 * 4 + g) * 96 + ch];
        kmbuf[j] = acc * invN;
    }
}

// ---------------------------------------------------------------- pass 2 (MFMA)
__global__ __launch_bounds__(256, 2)
void pass2_kernel(const unsigned short* __restrict__ qbuf, const unsigned short* __restrict__ vbuf,
                  const float* __restrict__ kvbuf, const float* __restrict__ kmbuf,
                  const float* __restrict__ csT, const float* __restrict__ snT,
                  const float* __restrict__ lw, const float* __restrict__ lb,
                  float* __restrict__ out)
{
    __shared__ alignas(16) unsigned short qls[64 * 104];   // 13312 B
    __shared__ alignas(16) unsigned short kvh[3840];       // [h*32+e][40] + d   (7680 B)
    __shared__ alignas(16) unsigned short kvl[3840];       // lo residual
    __shared__ alignas(16) float osmT[96 * 66];            // 25344 B
    __shared__ float zsh[192];
    __shared__ float lwL[864], lbL[96], kmL[96];

    const int tid = threadIdx.x, l = tid & 63, w = tid >> 6;
    const int tile = blockIdx.x, b = blockIdx.y, s = blockIdx.z, so = 1 - s;
    const int n0 = tile * 64;
    const int sb = s * B_ + b, sbo = so * B_ + b;

    // stage kv (hi/lo bf16, transposed to [e][d])
    const float* kvsrc = kvbuf + (size_t)sbo * 3072;
    for (int i = tid; i < 3072; i += 256) {
        float vkv = kvsrc[i];
        int h = i >> 10, d = (i >> 5) & 31, e = i & 31;
        unsigned short hi = f2bf(vkv);
        kvh[(h * 32 + e) * 40 + d] = hi;
        kvl[(h * 32 + e) * 40 + d] = f2bf(vkv - bf2f(hi));
    }
    for (int i = tid; i < 864; i += 256) lwL[i] = lw[i];
    if (tid < 96) { lbL[tid] = lb[tid]; kmL[tid] = kmbuf[sbo * 96 + tid]; }
    // stage q tile
    const unsigned short* qb = qbuf + ((size_t)sb * N_ + n0) * 96;
    for (int i = tid; i < 768; i += 256) {
        int row = i / 12, seg = i - row * 12;
        *(s16x8*)&qls[row * 104 + seg * 8] = *(const s16x8*)&qb[row * 96 + seg * 8];
    }
    __syncthreads();
    // z from raw q (pre-rope) vs other-stream kmean
    if (tid < 192) {
        int hh = tid >> 6, r = tid & 63;
        float a = 0.f;
        for (int d = 0; d < 32; ++d)
            a += bf2f(qls[r * 104 + hh * 32 + d]) * kmL[hh * 32 + d];
        zsh[hh * 64 + r] = 1.f / (a + 1e-6f);
    }
    __syncthreads();
    // rope q in place
#pragma unroll
    for (int it = 0; it < 12; ++it) {
        int u = it * 256 + tid;
        int r = u & 63, p = u >> 6;
        float c = csT[(size_t)p * N_ + n0 + r];
        float sv = snT[(size_t)p * N_ + n0 + r];
        unsigned int pr = *(unsigned int*)&qls[r * 104 + 2 * p];
        float re = bf2f((unsigned short)(pr & 0xFFFFu));
        float im = bf2f((unsigned short)(pr >> 16));
        unsigned int o0 = f2bf(c * re - sv * im);
        unsigned int o1 = f2bf(sv * re + c * im);
        *(unsigned int*)&qls[r * 104 + 2 * p] = o0 | (o1 << 16);
    }
    __syncthreads();
    // o = rope(q) @ kv (hi+lo) ; scale by z ; write transposed to osmT
    f32x4 oac[3][2] = {};
#pragma unroll
    for (int h = 0; h < 3; ++h) {
        s16x8 a = *(const s16x8*)&qls[(16 * w + (l & 15)) * 104 + h * 32 + 8 * (l >> 4)];
#pragma unroll
        for (int eT = 0; eT < 2; ++eT) {
            int rowb = (h * 32 + eT * 16 + (l & 15)) * 40 + 8 * (l >> 4);
            MFMA(oac[h][eT], a, *(const s16x8*)&kvh[rowb]);
            MFMA(oac[h][eT], a, *(const s16x8*)&kvl[rowb]);
        }
    }
#pragma unroll
    for (int h = 0; h < 3; ++h) {
#pragma unroll
        for (int i2 = 0; i2 < 4; ++i2) {
            int row = 16 * w + 4 * (l >> 4) + i2;
            float z = zsh[h * 64 + row];
            osmT[(h * 32 + (l & 15)) * 66 + row] = oac[h][0][i2] * z;
            osmT[(h * 32 + 16 + (l & 15)) * 66 + row] = oac[h][1][i2] * z;
        }
    }
    __syncthreads();
    // LePE conv add (ch-fast: coalesced v reads)
    const unsigned short* vb = vbuf + (size_t)sb * N_ * 96;
#pragma unroll
    for (int it = 0; it < 24; ++it) {
        int u = it * 256 + tid;
        int ch = u % 96, r = u / 96;
        int npos = n0 + r, ih = npos / 160, iw = npos - ih * 160;
        float a = lbL[ch];
#pragma unroll
        for (int ky = 0; ky < 3; ++ky) {
            int ih2 = ih + ky - 1;
            if ((unsigned)ih2 >= 120u) continue;
            const unsigned short* vrow = vb + (size_t)ih2 * 160 * 96 + ch;
#pragma unroll
            for (int kx = 0; kx < 3; ++kx) {
                int iw2 = iw + kx - 1;
                if ((unsigned)iw2 >= 160u) continue;
                a = fmaf(bf2f(vrow[(size_t)iw2 * 96]), lwL[ch * 9 + ky * 3 + kx], a);
            }
        }
        osmT[ch * 66 + r] += a;
    }
    __syncthreads();
    // store transposed: out[sb][ch][n]
    float* ob = out + (size_t)sb * 96 * N_;
#pragma unroll
    for (int it = 0; it < 24; ++it) {
        int u = it * 256 + tid;
        int r = u & 63, ch = u >> 6;
        ob[(size_t)ch * N_ + n0 + r] = osmT[ch * 66 + r];
    }
}

// ---------------------------------------------------------------- launch
extern "C" void kernel_launch(void* const* d_in, const int* in_sizes, int n_in,
                              void* d_out, int out_size, void* d_ws, size_t ws_size,
                              hipStream_t stream)
{
    const float* x1  = (const float*)d_in[0];
    const float* x2  = (const float*)d_in[1];
    const float* Wqk = (const float*)d_in[2];
    const float* bqk = (const float*)d_in[3];
    const float* Wv  = (const float*)d_in[4];
    const float* bv  = (const float*)d_in[5];
    const float* lw  = (const float*)d_in[6];
    const float* lb  = (const float*)d_in[7];
    float* out = (float*)d_out;

    char* ws = (char*)d_ws;
    size_t off = 0;
    auto alloc = [&](size_t bytes) -> void* {
        void* p = ws + off;
        off = (off + bytes + 255) & ~(size_t)255;
        return p;
    };
    float* csT = (float*)alloc(sizeof(float) * (size_t)N_ * 48);
    float* snT = (float*)alloc(sizeof(float) * (size_t)N_ * 48);
    unsigned short* qbuf = (unsigned short*)alloc(2ull * B_ * N_ * 96 * 2);
    unsigned short* vbuf = (unsigned short*)alloc(2ull * B_ * N_ * 96 * 2);
    float* kvpart = (float*)alloc(16ull * GX1 * 3072 * 4);
    float* kmpart = (float*)alloc(16ull * GX1 * 4 * 96 * 4);
    float* kvbuf  = (float*)alloc(16ull * 3072 * 4);
    float* kmbuf  = (float*)alloc(16ull * 96 * 4);

    hipLaunchKernelGGL(rope_table_kernel, dim3((48 * N_ + 255) / 256), dim3(256), 0, stream, csT, snT);
    hipLaunchKernelGGL(pass1_kernel, dim3(GX1, B_, 2), dim3(256), 0, stream,
                       x1, x2, Wqk, bqk, Wv, bv, csT, snT, qbuf, vbuf, kvpart, kmpart);
    hipLaunchKernelGGL(reduce_kernel, dim3((16 * 3072 + 16 * 96 + 255) / 256), dim3(256), 0, stream,
                       kvpart, kmpart, kvbuf, kmbuf);
    hipLaunchKernelGGL(pass2_kernel, dim3(NT2, B_, 2), dim3(256), 0, stream,
                       qbuf, vbuf, kvbuf, kmbuf, csT, snT, lw, lb, out);
}

// Round 4
// 272.551 us; speedup vs baseline: 4.2830x; 2.8130x over previous
//
#include <hip/hip_runtime.h>
#include <hip/hip_bf16.h>

// Problem constants (fixed by setup_inputs)
constexpr int B_ = 8;
constexpr int H_ = 120;
constexpr int W_ = 160;
constexpr int N_ = H_ * W_;     // 19200
constexpr int C_ = 96;

constexpr int GX1 = 75;         // pass1 blocks per (s,b)
constexpr int TPB1 = 4;         // tiles of 64 rows per block
constexpr int NT2 = N_ / 64;    // 300

typedef __attribute__((ext_vector_type(8))) short s16x8;
typedef __attribute__((ext_vector_type(4))) float f32x4;

static __device__ inline unsigned short f2bf(float f) {
    unsigned u = __float_as_uint(f);
    return (unsigned short)((u + 0x7FFFu + ((u >> 16) & 1u)) >> 16);
}
static __device__ inline float bf2f(unsigned short h) {
    return __uint_as_float(((unsigned)h) << 16);
}
static __device__ inline void MFMA(f32x4& c, s16x8 a, s16x8 b) {
    c = __builtin_amdgcn_mfma_f32_16x16x32_bf16(a, b, c, 0, 0, 0);
}
// frag-order LDS index for [96ch][64r] bf16 tiles:
// addr = (((r>>5)*6 + chT)*64 + ((r>>3)&3)*16 + chLo)*8 + (r&7)
static __device__ inline int kvidx(int chT, int chLo, int r) {
    return ((r >> 5) * 6 + chT) * 512 + ((r >> 3) & 3) * 128 + chLo * 8 + (r & 7);
}

// ---------------------------------------------------------------- rope tables (transposed: [48][N])
__global__ void rope_table_kernel(float* __restrict__ csT, float* __restrict__ snT) {
    int idx = blockIdx.x * 256 + threadIdx.x;
    if (idx >= 48 * N_) return;
    int p = idx / N_, n = idx - p * N_;
    int ih = n / W_, iw = n - ih * W_;
    int j = (p < 24) ? p : (p - 24);
    float pos = (p < 24) ? (float)ih : (float)iw;
    float theta = expf(-(float)j * (9.210340371976184f / 24.0f));
    float s, c;
    sincosf(pos * theta, &s, &c);
    csT[idx] = c;
    snT[idx] = s;
}

// ---------------------------------------------------------------- pass 1 (MFMA)
__global__ __launch_bounds__(256, 2)
void pass1_kernel(const float* __restrict__ x1, const float* __restrict__ x2,
                  const float* __restrict__ Wqk, const float* __restrict__ bqk,
                  const float* __restrict__ Wv, const float* __restrict__ bv,
                  const float* __restrict__ csT, const float* __restrict__ snT,
                  unsigned short* __restrict__ qbuf, unsigned short* __restrict__ vbuf,
                  float* __restrict__ kvpart, float* __restrict__ kmpart)
{
    __shared__ alignas(16) unsigned short Wl[27648];   // 55296 B, frag-order [3 ks][18 cT][64 lane][8]
    __shared__ alignas(16) unsigned short kTl[6144];   // 12288 B, frag-order [96ch][64r]
    __shared__ alignas(16) unsigned short vTl[6144];   // 12288 B

    const int tid = threadIdx.x;
    const int l = tid & 63, w = tid >> 6;
    const int gx = blockIdx.x, b = blockIdx.y, s = blockIdx.z;
    const float* x = s ? x2 : x1;
    const int sb = s * B_ + b;

    // stage W in fragment order (bf16)
    for (int i = tid; i < 3456; i += 256) {
        int s3 = i / 1152, rem = i - s3 * 1152;
        int cT = rem >> 6, lane = rem & 63;
        int col = cT * 16 + (lane & 15), k0 = s3 * 32 + 8 * (lane >> 4);
        const float* wp = (col < 192) ? (Wqk + col * 96 + k0) : (Wv + (col - 192) * 96 + k0);
        f32x4 wa = *(const f32x4*)wp;
        f32x4 wb = *(const f32x4*)(wp + 4);
        s16x8 wf;
        wf[0] = (short)f2bf(wa[0]); wf[1] = (short)f2bf(wa[1]);
        wf[2] = (short)f2bf(wa[2]); wf[3] = (short)f2bf(wa[3]);
        wf[4] = (short)f2bf(wb[0]); wf[5] = (short)f2bf(wb[1]);
        wf[6] = (short)f2bf(wb[2]); wf[7] = (short)f2bf(wb[3]);
        *(s16x8*)&Wl[i * 8] = wf;
    }
    float biasv[18];
#pragma unroll
    for (int cT = 0; cT < 18; ++cT) {
        int col = cT * 16 + (l & 15);
        biasv[cT] = (col < 192) ? bqk[col] : bv[col - 192];
    }
    f32x4 kvacc[3] = {};
    float kmacc[6] = {};
    __syncthreads();

    for (int t = 0; t < TPB1; ++t) {
        const int n0 = (gx * TPB1 + t) * 64;
        // GEMM: wave w computes rows [16w,16w+16) x 288 cols
        f32x4 acc[18] = {};
        const float* xrow = x + ((size_t)b * N_ + n0 + 16 * w + (l & 15)) * 96 + 8 * (l >> 4);
#pragma unroll
        for (int s3 = 0; s3 < 3; ++s3) {
            f32x4 xa = *(const f32x4*)(xrow + s3 * 32);
            f32x4 xb = *(const f32x4*)(xrow + s3 * 32 + 4);
            s16x8 af;
            af[0] = (short)f2bf(xa[0]); af[1] = (short)f2bf(xa[1]);
            af[2] = (short)f2bf(xa[2]); af[3] = (short)f2bf(xa[3]);
            af[4] = (short)f2bf(xb[0]); af[5] = (short)f2bf(xb[1]);
            af[6] = (short)f2bf(xb[2]); af[7] = (short)f2bf(xb[3]);
#pragma unroll
            for (int cT = 0; cT < 18; ++cT) {
                s16x8 bf = *(const s16x8*)&Wl[((s3 * 18 + cT) * 64 + l) * 8];
                MFMA(acc[cT], af, bf);
            }
        }
        __syncthreads();   // prev tile's kv-MFMA reads of kTl/vTl complete

        // epilogue
        const int r0 = 16 * w + 4 * (l >> 4);
        unsigned short* qb = qbuf + ((size_t)sb * N_ + n0) * 96;
        unsigned short* vb = vbuf + ((size_t)sb * N_ + n0) * 96;
#pragma unroll
        for (int cT = 0; cT < 6; ++cT) {          // q: elu+1, store pre-rope
#pragma unroll
            for (int i2 = 0; i2 < 4; ++i2) {
                float q = acc[cT][i2] + biasv[cT];
                q = (q > 0.f) ? q + 1.f : __expf(q);
                qb[(size_t)(r0 + i2) * 96 + cT * 16 + (l & 15)] = f2bf(q);
            }
        }
#pragma unroll
        for (int cT = 6; cT < 12; ++cT) {         // k: elu+1, kmean, stage to LDS
            float colsum = 0.f;
#pragma unroll
            for (int i2 = 0; i2 < 4; ++i2) {
                float k = acc[cT][i2] + biasv[cT];
                k = (k > 0.f) ? k + 1.f : __expf(k);
                colsum += k;
                kTl[kvidx(cT - 6, l & 15, r0 + i2)] = f2bf(k);
            }
            colsum += __shfl_xor(colsum, 16, 64);
            colsum += __shfl_xor(colsum, 32, 64);
            kmacc[cT - 6] += colsum;
        }
#pragma unroll
        for (int cT = 12; cT < 18; ++cT) {        // v: store + stage to LDS
#pragma unroll
            for (int i2 = 0; i2 < 4; ++i2) {
                float v = acc[cT][i2] + biasv[cT];
                unsigned short hv = f2bf(v);
                vb[(size_t)(r0 + i2) * 96 + (cT - 12) * 16 + (l & 15)] = hv;
                vTl[kvidx(cT - 12, l & 15, r0 + i2)] = hv;
            }
        }
        __syncthreads();
        // rope k in LDS (channel pairs 2p,2p+1 = adjacent chunks)
        for (int u = tid; u < 384; u += 256) {
            int p = u % 48, sub = u / 48;
            int ks = sub >> 2, rg = sub & 3;
            int chunk = ((ks * 6 + (p >> 3)) << 6) + (rg << 4) + ((2 * p) & 15);
            s16x8 re8 = *(s16x8*)&kTl[chunk * 8];
            s16x8 im8 = *(s16x8*)&kTl[chunk * 8 + 8];
            const float* cp = csT + (size_t)p * N_ + n0 + ks * 32 + rg * 8;
            const float* sp = snT + (size_t)p * N_ + n0 + ks * 32 + rg * 8;
            f32x4 c0 = *(const f32x4*)cp, c1 = *(const f32x4*)(cp + 4);
            f32x4 s0 = *(const f32x4*)sp, s1 = *(const f32x4*)(sp + 4);
            s16x8 ro, io;
#pragma unroll
            for (int e = 0; e < 4; ++e) {
                float re = bf2f((unsigned short)re8[e]), im = bf2f((unsigned short)im8[e]);
                ro[e] = (short)f2bf(c0[e] * re - s0[e] * im);
                io[e] = (short)f2bf(s0[e] * re + c0[e] * im);
            }
#pragma unroll
            for (int e = 0; e < 4; ++e) {
                float re = bf2f((unsigned short)re8[e + 4]), im = bf2f((unsigned short)im8[e + 4]);
                ro[e + 4] = (short)f2bf(c1[e] * re - s1[e] * im);
                io[e + 4] = (short)f2bf(s1[e] * re + c1[e] * im);
            }
            *(s16x8*)&kTl[chunk * 8] = ro;
            *(s16x8*)&kTl[chunk * 8 + 8] = io;
        }
        __syncthreads();
        // kv += k_roped^T @ v  (wave w owns flat C-tiles {w, w+4, w+8})
#pragma unroll
        for (int j = 0; j < 3; ++j) {
            int f = w + 4 * j;
            int h = f >> 2, dT = (f >> 1) & 1, eT = f & 1;
#pragma unroll
            for (int ks = 0; ks < 2; ++ks) {
                s16x8 a = *(const s16x8*)&kTl[(((ks * 6 + (h * 2 + dT)) << 6) + l) * 8];
                s16x8 bb = *(const s16x8*)&vTl[(((ks * 6 + (h * 2 + eT)) << 6) + l) * 8];
                MFMA(kvacc[j], a, bb);
            }
        }
    }
    // write partials
    float* kvp = kvpart + ((size_t)sb * GX1 + gx) * 3072;
#pragma unroll
    for (int j = 0; j < 3; ++j) {
        int f = w + 4 * j;
        int h = f >> 2, dT = (f >> 1) & 1, eT = f & 1;
#pragma unroll
        for (int i2 = 0; i2 < 4; ++i2)
            kvp[h * 1024 + (dT * 16 + 4 * (l >> 4) + i2) * 32 + eT * 16 + (l & 15)] = kvacc[j][i2];
    }
    if (l < 16) {
        float* kmp = kmpart + ((size_t)((size_t)sb * GX1 + gx) * 4 + w) * 96;
#pragma unroll
        for (int j6 = 0; j6 < 6; ++j6) kmp[j6 * 16 + l] = kmacc[j6];
    }
}

// ---------------------------------------------------------------- reduce
__global__ void reduce_kernel(const float* __restrict__ kvpart, const float* __restrict__ kmpart,
                              float* __restrict__ kvbuf, float* __restrict__ kmbuf)
{
    int idx = blockIdx.x * 256 + threadIdx.x;
    const float invN = 1.0f / (float)N_;
    if (idx < 16 * 3072) {
        int sb = idx / 3072, e = idx - sb * 3072;
        float acc = 0.f;
        for (int g = 0; g < GX1; ++g) acc += kvpart[((size_t)sb * GX1 + g) * 3072 + e];
        kvbuf[idx] = acc * invN;
    } else if (idx < 16 * 3072 + 16 * 96) {
        int j = idx - 16 * 3072;
        int sb = j / 96, ch = j - sb * 96;
        float acc = 0.f;
        for (int g = 0; g < GX1 * 4; ++g) acc += kmpart[((size_t)sb * GX1 * 4 + g) * 96 + ch];
        kmbuf[j] = acc * invN;
    }
}

// ---------------------------------------------------------------- pass 2 (MFMA)
__global__ __launch_bounds__(256, 3)
void pass2_kernel(const unsigned short* __restrict__ qbuf, const unsigned short* __restrict__ vbuf,
                  const float* __restrict__ kvbuf, const float* __restrict__ kmbuf,
                  const float* __restrict__ csT, const float* __restrict__ snT,
                  const float* __restrict__ lw, const float* __restrict__ lb,
                  float* __restrict__ out)
{
    __shared__ alignas(16) unsigned short qls[64 * 104];   // 13312 B
    __shared__ alignas(16) unsigned short kvh[3840];       // [h*32+e][40] + d   (7680 B)
    __shared__ alignas(16) float osmT[96 * 66];            // 25344 B
    __shared__ float zsh[192];
    __shared__ float lwL[864], lbL[96], kmL[96];

    const int tid = threadIdx.x, l = tid & 63, w = tid >> 6;
    const int tile = blockIdx.x, b = blockIdx.y, s = blockIdx.z, so = 1 - s;
    const int n0 = tile * 64;
    const int sb = s * B_ + b, sbo = so * B_ + b;

    // stage kv (bf16, transposed to [e][d])
    const float* kvsrc = kvbuf + (size_t)sbo * 3072;
    for (int i = tid; i < 3072; i += 256) {
        float vkv = kvsrc[i];
        int h = i >> 10, d = (i >> 5) & 31, e = i & 31;
        kvh[(h * 32 + e) * 40 + d] = f2bf(vkv);
    }
    for (int i = tid; i < 864; i += 256) lwL[i] = lw[i];
    if (tid < 96) { lbL[tid] = lb[tid]; kmL[tid] = kmbuf[sbo * 96 + tid]; }
    // stage q tile
    const unsigned short* qb = qbuf + ((size_t)sb * N_ + n0) * 96;
    for (int i = tid; i < 768; i += 256) {
        int row = i / 12, seg = i - row * 12;
        *(s16x8*)&qls[row * 104 + seg * 8] = *(const s16x8*)&qb[row * 96 + seg * 8];
    }
    __syncthreads();
    // z from raw q (pre-rope) vs other-stream kmean
    if (tid < 192) {
        int hh = tid >> 6, r = tid & 63;
        float a = 0.f;
        for (int d = 0; d < 32; ++d)
            a += bf2f(qls[r * 104 + hh * 32 + d]) * kmL[hh * 32 + d];
        zsh[hh * 64 + r] = 1.f / (a + 1e-6f);
    }
    __syncthreads();
    // rope q in place
#pragma unroll
    for (int it = 0; it < 12; ++it) {
        int u = it * 256 + tid;
        int r = u & 63, p = u >> 6;
        float c = csT[(size_t)p * N_ + n0 + r];
        float sv = snT[(size_t)p * N_ + n0 + r];
        unsigned int pr = *(unsigned int*)&qls[r * 104 + 2 * p];
        float re = bf2f((unsigned short)(pr & 0xFFFFu));
        float im = bf2f((unsigned short)(pr >> 16));
        unsigned int o0 = f2bf(c * re - sv * im);
        unsigned int o1 = f2bf(sv * re + c * im);
        *(unsigned int*)&qls[r * 104 + 2 * p] = o0 | (o1 << 16);
    }
    __syncthreads();
    // o = rope(q) @ kv ; scale by z ; write transposed to osmT
    f32x4 oac[3][2] = {};
#pragma unroll
    for (int h = 0; h < 3; ++h) {
        s16x8 a = *(const s16x8*)&qls[(16 * w + (l & 15)) * 104 + h * 32 + 8 * (l >> 4)];
#pragma unroll
        for (int eT = 0; eT < 2; ++eT) {
            int rowb = (h * 32 + eT * 16 + (l & 15)) * 40 + 8 * (l >> 4);
            MFMA(oac[h][eT], a, *(const s16x8*)&kvh[rowb]);
        }
    }
#pragma unroll
    for (int h = 0; h < 3; ++h) {
#pragma unroll
        for (int i2 = 0; i2 < 4; ++i2) {
            int row = 16 * w + 4 * (l >> 4) + i2;
            float z = zsh[h * 64 + row];
            osmT[(h * 32 + (l & 15)) * 66 + row] = oac[h][0][i2] * z;
            osmT[(h * 32 + 16 + (l & 15)) * 66 + row] = oac[h][1][i2] * z;
        }
    }
    __syncthreads();
    // LePE conv add: 768 ch-octets (64 r x 12 octets), ch-fast for coalescing,
    // u16x8 vector loads (27 per thread instead of 216 scalar)
    const unsigned short* vb = vbuf + (size_t)sb * (size_t)N_ * 96;
#pragma unroll
    for (int it = 0; it < 3; ++it) {
        int oct = it * 256 + tid;
        int r = oct / 12, c8 = oct - r * 12;
        int ch0 = c8 * 8;
        int npos = n0 + r, ih = npos / 160, iw = npos - ih * 160;
        float a[8];
#pragma unroll
        for (int e = 0; e < 8; ++e) a[e] = lbL[ch0 + e];
#pragma unroll
        for (int ky = 0; ky < 3; ++ky) {
            int ih2 = ih + ky - 1;
            if ((unsigned)ih2 >= 120u) continue;
#pragma unroll
            for (int kx = 0; kx < 3; ++kx) {
                int iw2 = iw + kx - 1;
                if ((unsigned)iw2 >= 160u) continue;
                s16x8 vv = *(const s16x8*)&vb[((size_t)ih2 * 160 + iw2) * 96 + ch0];
#pragma unroll
                for (int e = 0; e < 8; ++e)
                    a[e] = fmaf(bf2f((unsigned short)vv[e]), lwL[(ch0 + e) * 9 + ky * 3 + kx], a[e]);
            }
        }
#pragma unroll
        for (int e = 0; e < 8; ++e) osmT[(ch0 + e) * 66 + r] += a[e];
    }
    __syncthreads();
    // store transposed: out[sb][ch][n0+r], f32x4 over r
    float* ob = out + (size_t)sb * 96 * N_ + n0;
#pragma unroll
    for (int it = 0; it < 6; ++it) {
        int qq = it * 256 + tid;
        int r4 = (qq & 15) * 4, ch = qq >> 4;
        f32x4 vv;
        vv[0] = osmT[ch * 66 + r4];
        vv[1] = osmT[ch * 66 + r4 + 1];
        vv[2] = osmT[ch * 66 + r4 + 2];
        vv[3] = osmT[ch * 66 + r4 + 3];
        *(f32x4*)&ob[(size_t)ch * N_ + r4] = vv;
    }
}

// ---------------------------------------------------------------- launch
extern "C" void kernel_launch(void* const* d_in, const int* in_sizes, int n_in,
                              void* d_out, int out_size, void* d_ws, size_t ws_size,
                              hipStream_t stream)
{
    const float* x1  = (const float*)d_in[0];
    const float* x2  = (const float*)d_in[1];
    const float* Wqk = (const float*)d_in[2];
    const float* bqk = (const float*)d_in[3];
    const float* Wv  = (const float*)d_in[4];
    const float* bv  = (const float*)d_in[5];
    const float* lw  = (const float*)d_in[6];
    const float* lb  = (const float*)d_in[7];
    float* out = (float*)d_out;

    char* ws = (char*)d_ws;
    size_t off = 0;
    auto alloc = [&](size_t bytes) -> void* {
        void* p = ws + off;
        off = (off + bytes + 255) & ~(size_t)255;
        return p;
    };
    float* csT = (float*)alloc(sizeof(float) * (size_t)N_ * 48);
    float* snT = (float*)alloc(sizeof(float) * (size_t)N_ * 48);
    unsigned short* qbuf = (unsigned short*)alloc(2ull * B_ * N_ * 96 * 2);
    unsigned short* vbuf = (unsigned short*)alloc(2ull * B_ * N_ * 96 * 2);
    float* kvpart = (float*)alloc(16ull * GX1 * 3072 * 4);
    float* kmpart = (float*)alloc(16ull * GX1 * 4 * 96 * 4);
    float* kvbuf  = (float*)alloc(16ull * 3072 * 4);
    float* kmbuf  = (float*)alloc(16ull * 96 * 4);

    hipLaunchKernelGGL(rope_table_kernel, dim3((48 * N_ + 255) / 256), dim3(256), 0, stream, csT, snT);
    hipLaunchKernelGGL(pass1_kernel, dim3(GX1, B_, 2), dim3(256), 0, stream,
                       x1, x2, Wqk, bqk, Wv, bv, csT, snT, qbuf, vbuf, kvpart, kmpart);
    hipLaunchKernelGGL(reduce_kernel, dim3((16 * 3072 + 16 * 96 + 255) / 256), dim3(256), 0, stream,
                       kvpart, kmpart, kvbuf, kmbuf);
    hipLaunchKernelGGL(pass2_kernel, dim3(NT2, B_, 2), dim3(256), 0, stream,
                       qbuf, vbuf, kvbuf, kmbuf, csT, snT, lw, lb, out);
}